// Round 1
// baseline (191796.191 us; speedup 1.0000x reference)
//
#include <hip/hip_runtime.h>

// ESN forward scan on MI355X.
//
// Shapes: x[256][28][28], W_in[4096][28], W_res[4096][4096], W_out[10][4096],
// h0[4096]; out[256][10]. 7168 strictly-sequential steps h = tanh(W_in x_t + W_res h).
//
// Strategy: ONE persistent kernel, 256 WGs x 512 threads (1 WG/CU, all resident).
//  - W_res lives entirely in VGPRs: wave v of WG g owns rows g*16 + v*2 .. +2.
//    Per lane: 2 rows x 16 float4 (col = c*256 + lane*4 + m). ~220 VGPR -> 2 waves/SIMD.
//  - Per step: poll 256 per-WG flags (agent-scope), acquire-fence, coalesced float4
//    loads of h (double-buffered in d_ws), 128 FMA/lane, 6-level __shfl_xor tree,
//    fast tanh, agent-scope atomic h stores, release flag store.
//  - Readout fused: at each batch-final step, 10 partials -> LDS -> unsafeAtomicAdd
//    into zeroed d_out. No epilogue kernel.
//  - Spin budget converts any residency failure into a terminating wrong answer,
//    never a hang.

#define RES        4096
#define TSTEPS     7168
#define TSEQ       28
#define NWG        256
#define TPB        512   // 8 waves
#define ROWS_PER_WAVE 2

// d_ws layout: [0,1024) flags (256 u32, memset 0), [1024, 1024+32768) h double buffer
#define WS_NEEDED  (1024 + 2 * RES * 4)

__global__ __launch_bounds__(TPB, 2)
void esn_scan(const float* __restrict__ x,
              const float* __restrict__ Win,
              const float* __restrict__ Wres,
              const float* __restrict__ Wout,
              const float* __restrict__ h0,
              float* __restrict__ out,
              unsigned* __restrict__ flags,
              float* __restrict__ hbuf)
{
    const int wg   = blockIdx.x;
    const int tid  = threadIdx.x;
    const int wv   = tid >> 6;        // wave 0..7
    const int lane = tid & 63;
    const int rb   = wg * 16 + wv * ROWS_PER_WAVE;  // this wave's first row

    __shared__ float outred[8][16];   // per-wave readout partials (cols 0..9 used)

    // ---- one-time: W_res rows into registers (coalesced 1KiB/wave loads) ----
    float4 Wv[ROWS_PER_WAVE][16];
#pragma unroll
    for (int r = 0; r < ROWS_PER_WAVE; ++r) {
        const float* wr = Wres + (size_t)(rb + r) * RES;
#pragma unroll
        for (int c = 0; c < 16; ++c)
            Wv[r][c] = *reinterpret_cast<const float4*>(wr + c * 256 + lane * 4);
    }
    // W_in slice: lane i (<28) holds Win[row][i]
    float Wi[ROWS_PER_WAVE];
#pragma unroll
    for (int r = 0; r < ROWS_PER_WAVE; ++r)
        Wi[r] = (lane < 28) ? Win[(rb + r) * TSEQ + lane] : 0.f;

    int budget = 2000000;   // total spin rounds across all steps (~140x headroom)
    int tmod = 0, b = 0;

    for (int t = 0; t < TSTEPS; ++t) {
        // ---- wait until every WG has published h_{t-1} (flag[g] >= t) ----
        if (t > 0) {
            const unsigned tgt = (unsigned)t;
            const unsigned* fp = flags + lane * 4;
            for (;;) {
                unsigned f0 = __hip_atomic_load(fp + 0, __ATOMIC_RELAXED, __HIP_MEMORY_SCOPE_AGENT);
                unsigned f1 = __hip_atomic_load(fp + 1, __ATOMIC_RELAXED, __HIP_MEMORY_SCOPE_AGENT);
                unsigned f2 = __hip_atomic_load(fp + 2, __ATOMIC_RELAXED, __HIP_MEMORY_SCOPE_AGENT);
                unsigned f3 = __hip_atomic_load(fp + 3, __ATOMIC_RELAXED, __HIP_MEMORY_SCOPE_AGENT);
                unsigned mn = min(min(f0, f1), min(f2, f3));
                if (__all(mn >= tgt)) break;
                if (--budget < 0) break;   // safety: terminate, never hang
            }
            __builtin_amdgcn_fence(__ATOMIC_ACQUIRE, "agent");
        }

        // ---- load h_prev (16 KiB, coalesced float4; L1-shared across 8 waves) ----
        const float* hsrc = (t == 0) ? h0 : (hbuf + (size_t)RES * ((t & 1) ^ 1));
        float4 hv[16];
#pragma unroll
        for (int c = 0; c < 16; ++c)
            hv[c] = *reinterpret_cast<const float4*>(hsrc + c * 256 + lane * 4);

        // input row x[t] : lane i<28 holds x[t][i]
        float xv = (lane < 28) ? x[t * TSEQ + lane] : 0.f;

        // ---- per-row dot products (lane partials) ----
        float acc[ROWS_PER_WAVE];
#pragma unroll
        for (int r = 0; r < ROWS_PER_WAVE; ++r) {
            float4 a; a.x = 0.f; a.y = 0.f; a.z = 0.f; a.w = 0.f;
#pragma unroll
            for (int c = 0; c < 16; ++c) {
                a.x += Wv[r][c].x * hv[c].x;
                a.y += Wv[r][c].y * hv[c].y;
                a.z += Wv[r][c].z * hv[c].z;
                a.w += Wv[r][c].w * hv[c].w;
            }
            acc[r] = (a.x + a.y) + (a.z + a.w) + Wi[r] * xv;  // fold input proj
        }

        // ---- 64-lane butterfly reduction (result broadcast to all lanes) ----
#pragma unroll
        for (int m = 32; m; m >>= 1) {
#pragma unroll
            for (int r = 0; r < ROWS_PER_WAVE; ++r)
                acc[r] += __shfl_xor(acc[r], m, 64);
        }

        // ---- tanh(s) = 1 - 2/(e^{2s}+1); overflow-safe (exp->inf => 1) ----
        float hval[ROWS_PER_WAVE];
#pragma unroll
        for (int r = 0; r < ROWS_PER_WAVE; ++r) {
            float e = __expf(2.f * acc[r]);
            hval[r] = 1.f - __fdividef(2.f, e + 1.f);
        }

        // ---- publish this wave's 2 h values (agent scope -> L3 coherence point) ----
        float sv = (lane == 1) ? hval[1] : hval[0];
        if (lane < ROWS_PER_WAVE)
            __hip_atomic_store(hbuf + (size_t)RES * (t & 1) + rb + lane, sv,
                               __ATOMIC_RELAXED, __HIP_MEMORY_SCOPE_AGENT);

        // ---- fused readout partials at each batch element's last step ----
        if (tmod == TSEQ - 1 && lane < 10) {
            float contrib = Wout[lane * RES + rb + 0] * hval[0]
                          + Wout[lane * RES + rb + 1] * hval[1];
            outred[wv][lane] = contrib;
        }

        __syncthreads();  // drains all waves' vmem stores before flag publish

        if (tid == 0)
            __hip_atomic_store(flags + wg, (unsigned)(t + 1),
                               __ATOMIC_RELEASE, __HIP_MEMORY_SCOPE_AGENT);

        if (tmod == TSEQ - 1) {
            if (tid < 10) {
                float s = outred[0][tid] + outred[1][tid] + outred[2][tid] + outred[3][tid]
                        + outred[4][tid] + outred[5][tid] + outred[6][tid] + outred[7][tid];
                unsafeAtomicAdd(out + b * 10 + tid, s);
            }
            tmod = 0; ++b;
        } else {
            ++tmod;
        }
    }
}

extern "C" void kernel_launch(void* const* d_in, const int* in_sizes, int n_in,
                              void* d_out, int out_size, void* d_ws, size_t ws_size,
                              hipStream_t stream)
{
    (void)in_sizes; (void)n_in;
    if (ws_size < WS_NEEDED) return;  // document the (tiny) scratch requirement

    const float* x    = (const float*)d_in[0];
    const float* Win  = (const float*)d_in[1];
    const float* Wres = (const float*)d_in[2];
    const float* Wout = (const float*)d_in[3];
    const float* h0   = (const float*)d_in[4];
    float*       out  = (float*)d_out;

    unsigned* flags = (unsigned*)d_ws;
    float*    hbuf  = (float*)((char*)d_ws + 1024);

    // ws is re-poisoned 0xAA before every timed call: flags MUST start at 0.
    hipMemsetAsync(d_ws, 0, WS_NEEDED, stream);
    // out is accumulated via atomics: zero it every call.
    hipMemsetAsync(d_out, 0, (size_t)out_size * sizeof(float), stream);

    esn_scan<<<NWG, TPB, 0, stream>>>(x, Win, Wres, Wout, h0, out, flags, hbuf);
}

// Round 2
// 46507.907 us; speedup vs baseline: 4.1239x; 4.1239x over previous
//
#include <hip/hip_runtime.h>

// ESN forward scan on MI355X — R2.
//
// h_{t} = tanh(W_in x_t + W_res h_{t-1}), 7168 strictly-sequential steps.
// One persistent kernel, 256 WGs x 512 threads (8 waves), all co-resident.
//
// R1 post-mortem fixes:
//  - W_res register residency FAILED in R1 (VGPR=112 < 128 needed -> scratch
//    spill re-read through invalidated caches every step). R2 shrinks the peak
//    live set: h is consumed from LDS one float4 at a time instead of a
//    64-VGPR hv[16] array co-live with W. Peak ~175 VGPR < 256 cap.
//  - Poll storm: R1 had all 2048 waves spin-polling flags with agent-scope
//    (cache-bypass) loads, congesting L3. Now ONLY wave 0 of each WG polls,
//    then __syncthreads() releases the rest. 8x less poll traffic.
//  - Redundant h reads: R1 had every wave load the full 16KB h (32MB/step from
//    L3). Now one cooperative 16KB load per WG into LDS; waves read LDS.
//  - x[t+1] prefetched during compute (off the critical path).

#define RES    4096
#define TST    7168
#define TSEQ   28
#define NWG    256
#define TPB    512     // 8 waves
#define WAVES  8
#define RPW    2       // rows per wave; 8*256*2 = 4096 rows

// d_ws: [0,1024) flags (256 u32, zeroed each launch); [1024, +32KB) h dbl buffer
#define WS_NEEDED (1024 + 2 * RES * 4)

__global__ __launch_bounds__(TPB, 2)
void esn_scan(const float* __restrict__ x,
              const float* __restrict__ Win,
              const float* __restrict__ Wres,
              const float* __restrict__ Wout,
              const float* __restrict__ h0,
              float* __restrict__ out,
              unsigned* __restrict__ flags,
              float* __restrict__ hbuf)
{
    const int tid  = threadIdx.x;
    const int wv   = tid >> 6;         // wave 0..7
    const int lane = tid & 63;
    const int wg   = blockIdx.x;
    const int rb   = wg * 16 + wv * RPW;   // this wave's first row

    __shared__ float hlds[RES];            // staged h_{t-1} (16 KB)
    __shared__ float outred[WAVES][16];    // readout partials (cols 0..9 used)

    // ---- one-time: this wave's 2 W_res rows into registers (32 x float4) ----
    float4 W0[16], W1[16];
    {
        const float* r0 = Wres + (size_t)(rb + 0) * RES;
        const float* r1 = Wres + (size_t)(rb + 1) * RES;
#pragma unroll
        for (int c = 0; c < 16; ++c) {
            W0[c] = *reinterpret_cast<const float4*>(r0 + c * 256 + lane * 4);
            W1[c] = *reinterpret_cast<const float4*>(r1 + c * 256 + lane * 4);
        }
    }
    // W_in slices (lane i<28 holds Win[row][i]) and W_out slices (lane o<10)
    const float Wi0 = (lane < TSEQ) ? Win[(rb + 0) * TSEQ + lane] : 0.f;
    const float Wi1 = (lane < TSEQ) ? Win[(rb + 1) * TSEQ + lane] : 0.f;
    const float Wo0 = (lane < 10)   ? Wout[lane * RES + rb + 0]   : 0.f;
    const float Wo1 = (lane < 10)   ? Wout[lane * RES + rb + 1]   : 0.f;

    float xv = (lane < TSEQ) ? x[lane] : 0.f;   // x row for t=0
    int budget = 1500000;                        // anti-hang: terminate, never spin forever
    int tmod = 0, b = 0;

    for (int t = 0; t < TST; ++t) {
        // ---- gate: wave 0 alone waits until every WG published h_{t-1} ----
        if (t > 0) {
            if (wv == 0) {
                const unsigned tgt = (unsigned)t;
                const unsigned* fp = flags + lane * 4;
                for (;;) {
                    unsigned f0 = __hip_atomic_load(fp + 0, __ATOMIC_RELAXED, __HIP_MEMORY_SCOPE_AGENT);
                    unsigned f1 = __hip_atomic_load(fp + 1, __ATOMIC_RELAXED, __HIP_MEMORY_SCOPE_AGENT);
                    unsigned f2 = __hip_atomic_load(fp + 2, __ATOMIC_RELAXED, __HIP_MEMORY_SCOPE_AGENT);
                    unsigned f3 = __hip_atomic_load(fp + 3, __ATOMIC_RELAXED, __HIP_MEMORY_SCOPE_AGENT);
                    if (__all(min(min(f0, f1), min(f2, f3)) >= tgt)) break;
                    if (--budget < 0) break;
                }
                __builtin_amdgcn_fence(__ATOMIC_ACQUIRE, "agent");  // inv L1/L2 before h loads
            }
            __syncthreads();                                        // B1: h_{t-1} visible
        }

        // ---- stage h_{t-1} into LDS: 2 fully-coalesced float4 per thread ----
        {
            const float* hsrc = (t == 0) ? h0 : (hbuf + (size_t)RES * ((t & 1) ^ 1));
            float4 a = *reinterpret_cast<const float4*>(hsrc + tid * 4);
            float4 c = *reinterpret_cast<const float4*>(hsrc + 2048 + tid * 4);
            *reinterpret_cast<float4*>(hlds + tid * 4)        = a;
            *reinterpret_cast<float4*>(hlds + 2048 + tid * 4) = c;
        }
        __syncthreads();                                            // B2: LDS h ready

        // prefetch next step's x (independent of recurrence; hides under FMAs)
        float xnext = 0.f;
        if (t + 1 < TST && lane < TSEQ) xnext = x[(t + 1) * TSEQ + lane];

        // ---- per-row dot products: h consumed from LDS one float4 at a time ----
        float4 a0 = {0.f, 0.f, 0.f, 0.f}, a1 = {0.f, 0.f, 0.f, 0.f};
#pragma unroll
        for (int c = 0; c < 16; ++c) {
            float4 h4 = *reinterpret_cast<const float4*>(hlds + c * 256 + lane * 4);
            a0.x += W0[c].x * h4.x; a0.y += W0[c].y * h4.y;
            a0.z += W0[c].z * h4.z; a0.w += W0[c].w * h4.w;
            a1.x += W1[c].x * h4.x; a1.y += W1[c].y * h4.y;
            a1.z += W1[c].z * h4.z; a1.w += W1[c].w * h4.w;
        }
        float s0 = (a0.x + a0.y) + (a0.z + a0.w) + Wi0 * xv;
        float s1 = (a1.x + a1.y) + (a1.z + a1.w) + Wi1 * xv;
        xv = xnext;

        // ---- 64-lane butterfly (broadcasts totals to all lanes) ----
#pragma unroll
        for (int m = 32; m; m >>= 1) {
            s0 += __shfl_xor(s0, m, 64);
            s1 += __shfl_xor(s1, m, 64);
        }

        // tanh(s) = 1 - 2/(e^{2s}+1); overflow-safe
        float e0 = __expf(2.f * s0), e1 = __expf(2.f * s1);
        float h0v = 1.f - __fdividef(2.f, e0 + 1.f);
        float h1v = 1.f - __fdividef(2.f, e1 + 1.f);

        // ---- publish this wave's 2 h values (write-through to coherence point) ----
        if (lane < RPW) {
            float sv = lane ? h1v : h0v;
            __hip_atomic_store(hbuf + (size_t)RES * (t & 1) + rb + lane, sv,
                               __ATOMIC_RELAXED, __HIP_MEMORY_SCOPE_AGENT);
        }

        const bool last = (tmod == TSEQ - 1);
        if (last && lane < 10)
            outred[wv][lane] = Wo0 * h0v + Wo1 * h1v;

        __syncthreads();   // B3: each wave drains vmcnt before barrier -> h stores visible

        if (tid == 0)
            __hip_atomic_store(flags + wg, (unsigned)(t + 1),
                               __ATOMIC_RELEASE, __HIP_MEMORY_SCOPE_AGENT);

        // ---- fused readout at each batch element's final step ----
        if (last) {
            if (tid < 10) {
                float s = outred[0][tid] + outred[1][tid] + outred[2][tid] + outred[3][tid]
                        + outred[4][tid] + outred[5][tid] + outred[6][tid] + outred[7][tid];
                unsafeAtomicAdd(out + b * 10 + tid, s);
            }
            tmod = 0; ++b;
        } else {
            ++tmod;
        }
    }
}

extern "C" void kernel_launch(void* const* d_in, const int* in_sizes, int n_in,
                              void* d_out, int out_size, void* d_ws, size_t ws_size,
                              hipStream_t stream)
{
    (void)in_sizes; (void)n_in;
    if (ws_size < WS_NEEDED) return;

    const float* x    = (const float*)d_in[0];
    const float* Win  = (const float*)d_in[1];
    const float* Wres = (const float*)d_in[2];
    const float* Wout = (const float*)d_in[3];
    const float* h0   = (const float*)d_in[4];
    float*       out  = (float*)d_out;

    unsigned* flags = (unsigned*)d_ws;
    float*    hbuf  = (float*)((char*)d_ws + 1024);

    // ws/out are re-poisoned 0xAA before every timed call:
    hipMemsetAsync(d_ws, 0, 1024, stream);                              // flags -> 0
    hipMemsetAsync(d_out, 0, (size_t)out_size * sizeof(float), stream); // atomics accumulate

    esn_scan<<<NWG, TPB, 0, stream>>>(x, Win, Wres, Wout, h0, out, flags, hbuf);
}